// Round 4
// baseline (243.962 us; speedup 1.0000x reference)
//
#include <hip/hip_runtime.h>
#include <hip/hip_bf16.h>
#include <math.h>

// Problem constants
#define BB   16
#define CIN  16
#define HH   320
#define WW   320
#define OUTC 16
#define KK   4
#define HID  5
#define HWSZ (HH * WW)        // 102400

// Conv tiling
#define TW   64               // tile width (pixels)
#define TH   8                // tile height (rows)
#define LROW 66               // LDS row width in pixels (64 + 2 halo)
#define LROWS 10              // TH + 2 halo
#define NPIX (LROWS * LROW)   // 660 pixels per tile
#define NTASK (2 * NPIX)      // 1320 staging tasks (pixel x channel-half)
#define LDSN (2 * NPIX * 8)   // shorts: 10560 (21120 B)
#define KCH  5                // K chunks of 32 (K = 144 padded to 160)

typedef __attribute__((ext_vector_type(8))) short bf16x8_t;
typedef __attribute__((ext_vector_type(4))) float f32x4_t;

static __device__ __forceinline__ unsigned short f2bf(float f) {
    union { float f; unsigned u; } x; x.f = f;
    unsigned r = x.u + 0x7FFF + ((x.u >> 16) & 1);   // round-to-nearest-even
    return (unsigned short)(r >> 16);
}

static __device__ __forceinline__ unsigned pack_bf2(float a, float b) {
    __hip_bfloat162 q = __float22bfloat162_rn(make_float2(a, b));
    union { __hip_bfloat162 h; unsigned u; } cv; cv.h = q;
    return cv.u;
}

// ---------------------------------------------------------------------------
// Kernel 1: global average pool. One block per (b,c) plane, 1024 threads.
// ---------------------------------------------------------------------------
__global__ __launch_bounds__(1024)
void dg_pool_kernel(const float* __restrict__ x, float* __restrict__ pooled) {
    const int plane = blockIdx.x;              // b*CIN + c, 0..255
    const float4* p4 = (const float4*)(x + (size_t)plane * HWSZ);
    float s = 0.f;
    #pragma unroll 5
    for (int i = threadIdx.x; i < HWSZ / 4; i += 1024) {
        float4 v = p4[i];
        s += (v.x + v.y) + (v.z + v.w);
    }
    #pragma unroll
    for (int off = 32; off > 0; off >>= 1) s += __shfl_down(s, off, 64);
    __shared__ float red[16];
    if ((threadIdx.x & 63) == 0) red[threadIdx.x >> 6] = s;
    __syncthreads();
    if (threadIdx.x == 0) {
        float t = 0.f;
        #pragma unroll
        for (int i = 0; i < 16; ++i) t += red[i];
        pooled[plane] = t * (1.f / (float)HWSZ);
    }
}

// ---------------------------------------------------------------------------
// Kernel 2: attention MLP + scrambled softmax + expert mix, emitted directly
// in MFMA B-fragment lane order (bf16), K padded 144->160 with zeros.
// wB[b][kc][lane][j] : B[k = kc*32 + (lane>>4)*8 + j][n = lane&15]
//                    = wmix[o=n][c = k&15][tap = k>>4]
// One block per batch sample, 64 threads.
// ---------------------------------------------------------------------------
__global__ __launch_bounds__(64)
void dg_mix_kernel(const float* __restrict__ pooled,
                   const float* __restrict__ w1,
                   const float* __restrict__ w2,
                   const float* __restrict__ b2,
                   const float* __restrict__ weight,
                   unsigned short* __restrict__ wB) {
    const int b = blockIdx.x;
    const int tid = threadIdx.x;   // 0..63
    __shared__ float sm[64];
    __shared__ float coeff[64];    // flat softmax, (k*16+o) order

    float pb[CIN];
    #pragma unroll
    for (int c = 0; c < CIN; ++c) pb[c] = pooled[b * CIN + c];
    float hid[HID];
    #pragma unroll
    for (int h = 0; h < HID; ++h) {
        float a = 0.f;
        #pragma unroll
        for (int c = 0; c < CIN; ++c) a = fmaf(pb[c], w1[h * CIN + c], a);
        hid[h] = fmaxf(a, 0.f);
    }
    float a = b2[tid];
    #pragma unroll
    for (int h = 0; h < HID; ++h) a = fmaf(hid[h], w2[tid * HID + h], a);
    sm[tid] = a;
    __syncthreads();

    const int oa = tid & 15;
    float a0 = sm[oa], a1 = sm[16 + oa], a2 = sm[32 + oa], a3 = sm[48 + oa];
    float m = fmaxf(fmaxf(a0, a1), fmaxf(a2, a3));
    float denom = expf(a0 - m) + expf(a1 - m) + expf(a2 - m) + expf(a3 - m);
    coeff[tid] = expf(sm[tid] - m) / denom;
    __syncthreads();

    const int o = tid & 15;
    const int kbase = (tid >> 4) * 8;
    #pragma unroll
    for (int kc = 0; kc < KCH; ++kc) {
        unsigned short frag[8];
        #pragma unroll
        for (int j = 0; j < 8; ++j) {
            const int k = kc * 32 + kbase + j;
            float v = 0.f;
            if (k < 144) {
                const int tap = k >> 4;
                const int c = k & 15;
                const float* wp = weight + (((size_t)(o * CIN + c) * 9 + tap) << 2);
                v = coeff[o * 4 + 0] * wp[0] + coeff[o * 4 + 1] * wp[1]
                  + coeff[o * 4 + 2] * wp[2] + coeff[o * 4 + 3] * wp[3];
            }
            frag[j] = f2bf(v);
        }
        unsigned short* dst = wB + (((size_t)(b * KCH + kc) * 64) + tid) * 8;
        #pragma unroll
        for (int j = 0; j < 8; ++j) dst[j] = frag[j];
    }
}

// ---------------------------------------------------------------------------
// Kernel 3: implicit-GEMM conv via mfma_f32_16x16x32_bf16.
// Block = 256 thr (4 waves), tile = 64x8 pixels, per-b. 6 blocks/CU.
// LDS layout: [chalf][pixel][8ch] bf16 -> 16-B slot index S = chalf*NPIX + P.
// Staging task order == layout order => conflict-free ds_write_b128;
// A-reads: consecutive pixels -> consecutive slots (conflict-free).
// ---------------------------------------------------------------------------
__global__ __launch_bounds__(256, 6)
void dg_conv_kernel(const float* __restrict__ x,
                    const unsigned short* __restrict__ wB,
                    float* __restrict__ out) {
    const int b   = blockIdx.z;
    const int by0 = blockIdx.y * TH;
    const int bx0 = blockIdx.x * TW;
    const int tid = threadIdx.x;
    const int lane = tid & 63;
    const int wave = tid >> 6;

    __shared__ __align__(16) unsigned short sx[LDSN];

    // ---- B fragments (per-lane, coalesced 16-B global loads; L2-resident) ----
    bf16x8_t Bf[KCH];
    {
        const unsigned short* wBb = wB + (size_t)b * KCH * 512;
        #pragma unroll
        for (int kc = 0; kc < KCH; ++kc)
            Bf[kc] = *(const bf16x8_t*)(wBb + kc * 512 + lane * 8);
    }

    // ---- stage x tile -> LDS (bf16), conflict-free writes ----
    {
        const float* xb = x + (size_t)b * CIN * HWSZ;
        #pragma unroll 1
        for (int it = 0; it < (NTASK + 255) / 256; ++it) {
            const int t = tid + it * 256;
            if (t < NTASK) {
                const int half = (t >= NPIX) ? 1 : 0;
                const int P    = t - half * NPIX;
                const int row  = P / LROW;
                const int px   = P - row * LROW;
                const int gy = by0 - 1 + row;
                const int gx = bx0 - 1 + px;
                const bool valid = ((unsigned)gy < HH) && ((unsigned)gx < WW);
                const int gyc = valid ? gy : 0;
                const int gxc = valid ? gx : 0;
                const float* bp = xb + (size_t)(half * 8) * HWSZ
                                     + (size_t)gyc * WW + gxc;
                float v[8];
                #pragma unroll
                for (int j = 0; j < 8; ++j)
                    v[j] = valid ? bp[(size_t)j * HWSZ] : 0.f;
                union { bf16x8_t v8; unsigned u[4]; } pk;
                #pragma unroll
                for (int j = 0; j < 4; ++j)
                    pk.u[j] = pack_bf2(v[2 * j], v[2 * j + 1]);
                *(bf16x8_t*)&sx[(size_t)t * 8] = pk.v8;
            }
        }
    }

    // ---- per-lane A-fragment addressing constants ----
    const int m     = lane & 15;
    const int quad  = lane >> 4;
    const int chalf = quad & 1;
    int dP[KCH];
    #pragma unroll
    for (int kc = 0; kc < KCH; ++kc) {
        int t = 2 * kc + (quad >> 1);
        if (t > 8) t = 8;                 // k>=144: B is zero, clamp tap to stay in tile
        dP[kc] = (t / 3 - 1) * LROW + (t % 3 - 1);
    }
    const int hofs = chalf * NPIX;        // slot offset for channel half

    f32x4_t acc[8];
    #pragma unroll
    for (int i = 0; i < 8; ++i) acc[i] = (f32x4_t){0.f, 0.f, 0.f, 0.f};

    __syncthreads();

    // ---- main MFMA loop: 2 rows x 4 x-tiles x 5 K-chunks ----
    #pragma unroll
    for (int rr = 0; rr < 2; ++rr) {
        #pragma unroll
        for (int tx = 0; tx < 4; ++tx) {
            const int P0 = (2 * wave + rr + 1) * LROW + 1 + tx * 16 + m;
            #pragma unroll
            for (int kc = 0; kc < KCH; ++kc) {
                const int S = hofs + P0 + dP[kc];
                const bf16x8_t Af = *(const bf16x8_t*)&sx[(size_t)S * 8];
                acc[rr * 4 + tx] = __builtin_amdgcn_mfma_f32_16x16x32_bf16(
                    Af, Bf[kc], acc[rr * 4 + tx], 0, 0, 0);
            }
        }
    }

    // ---- epilogue: D layout col=lane&15=outc n, row=quad*4+reg=pixel ----
    const int n = lane & 15;
    float* ob = out + ((size_t)(b * OUTC + n)) * HWSZ;
    #pragma unroll
    for (int rr = 0; rr < 2; ++rr) {
        const int gy = by0 + 2 * wave + rr;
        #pragma unroll
        for (int tx = 0; tx < 4; ++tx) {
            const int gx = bx0 + tx * 16 + quad * 4;
            *(f32x4_t*)(ob + (size_t)gy * WW + gx) = acc[rr * 4 + tx];
        }
    }
}

// ---------------------------------------------------------------------------
extern "C" void kernel_launch(void* const* d_in, const int* in_sizes, int n_in,
                              void* d_out, int out_size, void* d_ws, size_t ws_size,
                              hipStream_t stream) {
    const float* x      = (const float*)d_in[0];
    const float* w1     = (const float*)d_in[1];
    const float* w2     = (const float*)d_in[2];
    const float* b2     = (const float*)d_in[3];
    const float* weight = (const float*)d_in[4];
    float* out = (float*)d_out;

    float* pooled = (float*)d_ws;                       // 256 floats
    unsigned short* wBf = (unsigned short*)((float*)d_ws + 256);  // 16*5*64*8 bf16 = 80 KB

    dg_pool_kernel<<<BB * CIN, 1024, 0, stream>>>(x, pooled);
    dg_mix_kernel<<<BB, 64, 0, stream>>>(pooled, w1, w2, b2, weight, wBf);
    dg_conv_kernel<<<dim3(WW / TW, HH / TH, BB), 256, 0, stream>>>(x, wBf, out);
}